// Round 1
// 5803.554 us; speedup vs baseline: 1.0509x; 1.0509x over previous
//
#include <hip/hip_runtime.h>
#include <hip/hip_bf16.h>

// theta_solver on MI355X — tr-subtiled LDS version.
// State y (fp32) in registers (MFMA C/D layout). f-inputs round-trip through
// LDS as bf16 in a transpose-subtiled layout: 16rowx16k blocks of 512B,
// element (row,k) at short offset row + 16*(k&3) + 64*(k>>2). Writes from the
// MFMA C-layout are packed ds_write_b64 (4 consecutive rows per lane); reads
// for the next GEMM's A-operand use ds_read_b64_tr_b16 (per-lane addr
// base+8*lane, block selected by offset: immediate). The k-slot permutation
// induced by the tr read (slot(q,j) <-> k = 4q+j j<4, 16+4q+(j-4) j>=4) is
// folded into the weight repack so MFMA results are unchanged.
// GEMM1 runs as 2 passes of 256 hidden cols (nt=4; A-frag reuse x4), GEMM2
// accumulates F over each pass's 256 k. 4 barriers/eval (was 9).

typedef short short8 __attribute__((ext_vector_type(8)));
typedef short short4_t __attribute__((ext_vector_type(4)));
typedef float floatx4 __attribute__((ext_vector_type(4)));

#define MFMA(a, b, c) __builtin_amdgcn_mfma_f32_16x16x32_bf16((a), (b), (c), 0, 0, 0)

__device__ __forceinline__ short f2bf(float f) {
    __hip_bfloat16 h = __float2bfloat16(f);
    return *reinterpret_cast<short*>(&h);
}

__device__ __forceinline__ float fast_tanh(float x) {
    float e = __expf(2.0f * x);
    return 1.0f - 2.0f * __builtin_amdgcn_rcpf(1.0f + e);
}

// Read one MFMA A-fragment (8 bf16) from a tr-subtiled LDS tile.
// Lane l elem j of ds_read_b64_tr_b16 with addr base+8*l returns
// block[(l&15) + 16*j + 64*(l>>4)] = A[row=l&15][k = 4*(l>>4)+j]
// (measured layout, learn_hip m156/m162). Two blocks give k=0..31 of a step.
#define TR8(dst, abase, B0, B1)                                             \
    do {                                                                    \
        short4_t lo_, hi_;                                                  \
        asm volatile("ds_read_b64_tr_b16 %0, %2 offset:%c3\n\t"             \
                     "ds_read_b64_tr_b16 %1, %2 offset:%c4"                 \
                     : "=&v"(lo_), "=&v"(hi_)                               \
                     : "v"(abase), "i"((B0) * 512), "i"((B1) * 512));       \
        dst = __builtin_shufflevector(lo_, hi_, 0, 1, 2, 3, 4, 5, 6, 7);    \
    } while (0)

// Wait for the asm ds_reads, then fence the scheduler so MFMAs can't hoist
// above the wait (compiler doesn't order reg-only MFMA vs inline-asm
// waitcnt). Mask 0x77 = ALU|VALU|SALU|VMEM may cross (W-streaming loads keep
// pipelining); MFMA (0x8) and DS (0x380) are pinned.
#define WAIT_TR()                              \
    do {                                       \
        asm volatile("s_waitcnt lgkmcnt(0)");  \
        __builtin_amdgcn_sched_barrier(0x77);  \
    } while (0)

// ---------------------------------------------------------------------------
// Weight repack into B-frag blocks with the tr-read k ordering:
// slot (q=lane>>4, j): k = 32*s + ((j>>2)<<4) + 4*q + (j&3).
// W1 [256x512]: block bi = ct*8 + s (ct = n>>4, s = kstep of 32).
// W2 [512x256]: block bi = ct*16 + s (s in 0..15).
// ---------------------------------------------------------------------------
__global__ void repack_weights(const float* __restrict__ W1,
                               const float* __restrict__ W2,
                               short* __restrict__ W1p,
                               short* __restrict__ W2p) {
    int t = blockIdx.x * blockDim.x + threadIdx.x;  // 0..32767
    int lane = t & 63;
    int q = lane >> 4, c = lane & 15;
    if (t < 16384) {
        int s = (t >> 6) & 7;
        int ct = t >> 9;  // 0..31
        short8 v;
#pragma unroll
        for (int j = 0; j < 8; ++j) {
            int k = 32 * s + ((j >> 2) << 4) + 4 * q + (j & 3);
            int n = 16 * ct + c;
            v[j] = f2bf(W1[k * 512 + n]);
        }
        *reinterpret_cast<short8*>(&W1p[t * 8]) = v;
    } else {
        int t2 = t - 16384;
        int s = (t2 >> 6) & 15;
        int ct = t2 >> 10;  // 0..15
        short8 v;
#pragma unroll
        for (int j = 0; j < 8; ++j) {
            int k = 32 * s + ((j >> 2) << 4) + 4 * q + (j & 3);
            int n = 16 * ct + c;
            v[j] = f2bf(W2[k * 256 + n]);
        }
        *reinterpret_cast<short8*>(&W2p[t2 * 8]) = v;
    }
}

__global__ __launch_bounds__(256, 2) void theta_main(
    const float* __restrict__ x,
    const float* __restrict__ b1,
    const float* __restrict__ b2,
    const short* __restrict__ W1p,
    const short* __restrict__ W2p,
    float* __restrict__ out) {
    __shared__ __align__(16) short Yb[16384];  // 64r x 256k tr-subtiled, 32 KB
    __shared__ __align__(16) short Hc[16384];  // 64r x 256k tr-subtiled, 32 KB

    const int tid = threadIdx.x;
    const int w = tid >> 6;
    const int lane = tid & 63;
    const int q = lane >> 4, c = lane & 15;
    const int row0 = blockIdx.x << 6;
    const float HT = 0.0625f;  // h*theta == h*(1-theta)

    // low 32 bits of a flat LDS address are the LDS byte offset on gfx9xx
    const uint32_t trY = (uint32_t)(uintptr_t)&Yb[0] + (lane << 3);
    const uint32_t trH = (uint32_t)(uintptr_t)&Hc[0] + (lane << 3);
    // packed-store slot within a 256-short block (4 consecutive rows of one k)
    const int wo = 4 * q + 16 * (c & 3) + 64 * (c >> 2);

    const floatx4 fz = {0.f, 0.f, 0.f, 0.f};

    // HT*b2 cached per thread (F-col = 64w+16nt+c is fixed per thread)
    float hb2c[4];
#pragma unroll
    for (int nt = 0; nt < 4; ++nt) hb2c[nt] = HT * b2[64 * w + 16 * nt + c];

    // y state in fp32, C-layout. Wave w owns cols [64w, 64w+64).
    float yv[4][4][4];
#pragma unroll
    for (int mt = 0; mt < 4; ++mt)
#pragma unroll
        for (int nt = 0; nt < 4; ++nt)
#pragma unroll
            for (int r = 0; r < 4; ++r)
                yv[mt][nt][r] = x[(row0 + 16 * mt + 4 * q + r) * 256 + 64 * w + 16 * nt + c];

    // initial Yb = bf16(x), tr-subtiled; packed b64 stores
#pragma unroll
    for (int mt = 0; mt < 4; ++mt)
#pragma unroll
        for (int nt = 0; nt < 4; ++nt) {
            short4_t v;
#pragma unroll
            for (int r = 0; r < 4; ++r) v[r] = f2bf(yv[mt][nt][r]);
            *reinterpret_cast<short4_t*>(&Yb[((mt * 16 + 4 * w + nt) << 8) + wo]) = v;
        }
    __syncthreads();

    floatx4 facc[4][4];

#pragma unroll 1
    for (int step = 0; step < 8; ++step) {
#pragma unroll 1
        for (int it = 0; it < 20; ++it) {
            // ---- one f-eval: facc = (tanh(Yb@W1+b1)@W2) (b2 added at use) ----
#pragma unroll
            for (int mt = 0; mt < 4; ++mt)
#pragma unroll
                for (int nt = 0; nt < 4; ++nt) facc[mt][nt] = fz;

#pragma unroll 1
            for (int p = 0; p < 2; ++p) {
                // pass-1 entry barrier: all waves done reading Hc (pass-0 GEMM2)
                if (p == 1) __syncthreads();

                float bv[4];  // b1 slice; issued early, consumed at tanh
#pragma unroll
                for (int nt = 0; nt < 4; ++nt)
                    bv[nt] = b1[p * 256 + 64 * w + 16 * nt + c];

                const short* w1b = W1p + (p * 16 + 4 * w) * 4096 + lane * 8;

                floatx4 g[4][4];
#pragma unroll
                for (int mt = 0; mt < 4; ++mt)
#pragma unroll
                    for (int nt = 0; nt < 4; ++nt) g[mt][nt] = fz;

                // ---- GEMM1: G[64 x 64/wave] over k=256 from Yb ----
#pragma unroll
                for (int s = 0; s < 8; ++s) {
                    short8 wb[4], a[4];
#pragma unroll
                    for (int nt = 0; nt < 4; ++nt)
                        wb[nt] = *reinterpret_cast<const short8*>(w1b + (nt * 8 + s) * 512);
                    TR8(a[0], trY, 0 * 16 + 2 * s, 0 * 16 + 2 * s + 1);
                    TR8(a[1], trY, 1 * 16 + 2 * s, 1 * 16 + 2 * s + 1);
                    TR8(a[2], trY, 2 * 16 + 2 * s, 2 * 16 + 2 * s + 1);
                    TR8(a[3], trY, 3 * 16 + 2 * s, 3 * 16 + 2 * s + 1);
                    WAIT_TR();
                    __builtin_amdgcn_s_setprio(1);
#pragma unroll
                    for (int mt = 0; mt < 4; ++mt)
#pragma unroll
                        for (int nt = 0; nt < 4; ++nt)
                            g[mt][nt] = MFMA(a[mt], wb[nt], g[mt][nt]);
                    __builtin_amdgcn_s_setprio(0);
                }

                // ---- tanh + packed b64 scatter into Hc (tr-subtiled) ----
#pragma unroll
                for (int mt = 0; mt < 4; ++mt)
#pragma unroll
                    for (int nt = 0; nt < 4; ++nt) {
                        short4_t v;
#pragma unroll
                        for (int r = 0; r < 4; ++r)
                            v[r] = f2bf(fast_tanh(g[mt][nt][r] + bv[nt]));
                        *reinterpret_cast<short4_t*>(&Hc[((mt * 16 + 4 * w + nt) << 8) + wo]) = v;
                    }
                __syncthreads();  // Hc pass complete for all waves

                // ---- GEMM2 partial: F[64 x 64/wave] += Hc @ W2(pass) ----
                const short* w2b = W2p + (64 * w + p * 8) * 512 + lane * 8;
#pragma unroll
                for (int ks = 0; ks < 8; ++ks) {
                    short8 wb[4], a[4];
#pragma unroll
                    for (int nt = 0; nt < 4; ++nt)
                        wb[nt] = *reinterpret_cast<const short8*>(w2b + (nt * 16 + ks) * 512);
                    TR8(a[0], trH, 0 * 16 + 2 * ks, 0 * 16 + 2 * ks + 1);
                    TR8(a[1], trH, 1 * 16 + 2 * ks, 1 * 16 + 2 * ks + 1);
                    TR8(a[2], trH, 2 * 16 + 2 * ks, 2 * 16 + 2 * ks + 1);
                    TR8(a[3], trH, 3 * 16 + 2 * ks, 3 * 16 + 2 * ks + 1);
                    WAIT_TR();
                    __builtin_amdgcn_s_setprio(1);
#pragma unroll
                    for (int mt = 0; mt < 4; ++mt)
#pragma unroll
                        for (int nt = 0; nt < 4; ++nt)
                            facc[mt][nt] = MFMA(a[mt], wb[nt], facc[mt][nt]);
                    __builtin_amdgcn_s_setprio(0);
                }
            }  // pass

            // ---- theta update + packed Yb write ----
            // it==0:  yv += d; z = yv + d   (expl and z1;  d = HT*(F+b2))
            // it 1..18: z = yv + d
            // it==19: yv += d; write yv     (y_{n+1})
            const bool first = (it == 0), last = (it == 19);
#pragma unroll
            for (int mt = 0; mt < 4; ++mt)
#pragma unroll
                for (int nt = 0; nt < 4; ++nt) {
                    short4_t zv;
#pragma unroll
                    for (int r = 0; r < 4; ++r) {
                        float dd = HT * facc[mt][nt][r] + hb2c[nt];
                        if (first || last) yv[mt][nt][r] += dd;
                        float zz = last ? yv[mt][nt][r] : yv[mt][nt][r] + dd;
                        zv[r] = f2bf(zz);
                    }
                    *reinterpret_cast<short4_t*>(&Yb[((mt * 16 + 4 * w + nt) << 8) + wo]) = zv;
                }
            __syncthreads();
        }  // it
    }  // step

    // ---- write yT ----
#pragma unroll
    for (int mt = 0; mt < 4; ++mt)
#pragma unroll
        for (int nt = 0; nt < 4; ++nt)
#pragma unroll
            for (int r = 0; r < 4; ++r)
                out[(row0 + 16 * mt + 4 * q + r) * 256 + 64 * w + 16 * nt + c] = yv[mt][nt][r];
}

extern "C" void kernel_launch(void* const* d_in, const int* in_sizes, int n_in,
                              void* d_out, int out_size, void* d_ws, size_t ws_size,
                              hipStream_t stream) {
    const float* x = (const float*)d_in[0];
    const float* W1 = (const float*)d_in[1];
    const float* b1 = (const float*)d_in[2];
    const float* W2 = (const float*)d_in[3];
    const float* b2 = (const float*)d_in[4];
    float* out = (float*)d_out;

    short* W1p = (short*)d_ws;     // 256*512 bf16 = 256 KB
    short* W2p = W1p + 256 * 512;  // 512*256 bf16 = 256 KB

    repack_weights<<<dim3(128), dim3(256), 0, stream>>>(W1, W2, W1p, W2p);
    theta_main<<<dim3(1024), dim3(256), 0, stream>>>(x, b1, b2, W1p, W2p, out);
}